// Round 2
// baseline (1773.131 us; speedup 1.0000x reference)
//
#include <hip/hip_runtime.h>
#include <stdint.h>

#define NBATCH 512
#define NT     2048
#define NK     8
#define ND     32

// One wave (64 lanes) per batch element b.
// lane = (i = lane&31 -> output dim, kh = lane>>5 -> k-half {0,1}, 4 k's each).
// Each lane holds A[kh*4+kk][i][0..31] in 128 f32 VGPRs (A never touches LDS/global in the loop).
// z is replicated across lanes (32 f32 regs); per-step broadcast via 256B LDS double buffer.
__global__ __launch_bounds__(64, 1) void slds_kernel(
    const float* __restrict__ z0,
    const float* __restrict__ s_probs,
    const float* __restrict__ noise,
    const float* __restrict__ A_s,
    const float* __restrict__ b_s,
    const float* __restrict__ Q_chol,
    float* __restrict__ ys)
{
    const int b    = blockIdx.x;
    const int lane = threadIdx.x;
    const int i    = lane & 31;
    const int kh   = lane >> 5;

    const float dt  = 0.05f;
    const float sdt = 0.22360679774997896f; // sqrt(0.05)

    // ---- load A slice into registers (f32), vectorized 16B loads ----
    float a[4][ND];
#pragma unroll
    for (int kk = 0; kk < 4; ++kk) {
        const float4* ap = (const float4*)(A_s + (((size_t)(kh * 4 + kk) * ND + i) * ND));
#pragma unroll
        for (int q = 0; q < 8; ++q) {
            float4 v = ap[q];
            a[kk][q * 4 + 0] = v.x;
            a[kk][q * 4 + 1] = v.y;
            a[kk][q * 4 + 2] = v.z;
            a[kk][q * 4 + 3] = v.w;
        }
    }
    float breg[4], qreg[4];
#pragma unroll
    for (int kk = 0; kk < 4; ++kk) {
        breg[kk] = b_s[(kh * 4 + kk) * ND + i];
        qreg[kk] = Q_chol[(kh * 4 + kk) * ND + i];
    }

    // ---- z: replicated copy + own element ----
    float z[ND];
#pragma unroll
    for (int j = 0; j < ND; ++j) z[j] = z0[b * ND + j];
    float zi = z0[b * ND + i];

    __shared__ __align__(16) float zs[2][ND];

    // s_probs: 8 f32 per (t,b) == two float4, wave-uniform address -> s_load_dwordx4
    const float4* wbase = (const float4*)s_probs;
    const float*  nbase = noise;

    // software prefetch of step-0 inputs
    float4 wp0 = wbase[(size_t)0 * NBATCH * 2 + b * 2 + 0];
    float4 wp1 = wbase[(size_t)0 * NBATCH * 2 + b * 2 + 1];
    float  nraw = nbase[((size_t)0 * NBATCH + b) * ND + i];

    int buf = 0;
    for (int t = 0; t < NT; ++t) {
        const float4 wa = wp0, wb = wp1;
        const float  nrc = nraw;
        if (t + 1 < NT) {  // prefetch next step (independent of z -> hides latency)
            wp0  = wbase[(size_t)(t + 1) * NBATCH * 2 + b * 2 + 0];
            wp1  = wbase[(size_t)(t + 1) * NBATCH * 2 + b * 2 + 1];
            nraw = nbase[((size_t)(t + 1) * NBATCH + b) * ND + i];
        }

        // 8 weights, wave-uniform values
        float w[8] = {wa.x, wa.y, wa.z, wa.w, wb.x, wb.y, wb.z, wb.w};
        float wsum = ((w[0] + w[1]) + (w[2] + w[3])) + ((w[4] + w[5]) + (w[6] + w[7]));
        float inv  = __builtin_amdgcn_rcpf(wsum);  // ~1 ulp, way under threshold

        // y_k[i] = sum_j A[k][i][j] * z[j]; accumulate w-weighted drift & diffusion
        float acc = 0.f, qacc = 0.f;
#pragma unroll
        for (int kk = 0; kk < 4; ++kk) {
            float y = 0.f;
#pragma unroll
            for (int j = 0; j < ND; ++j) y = fmaf(a[kk][j], z[j], y);
            float wk = (kh == 0) ? w[kk] : w[kk + 4];  // no dynamic reg indexing
            acc  = fmaf(wk, y + breg[kk], acc);
            qacc = fmaf(wk, qreg[kk], qacc);
        }

        // combine the two k-halves
        acc  += __shfl_xor(acc, 32);
        qacc += __shfl_xor(qacc, 32);

        float drift = acc * inv;
        float diffc = qacc * inv;
        float znew  = zi + dt * drift + diffc * (sdt * nrc);

        const size_t oofs = ((size_t)t * NBATCH + b) * ND + i;
        if (lane < 32) {
            ys[oofs]   = znew;   // f32 output
            zs[buf][i] = znew;   // publish for broadcast
        }
        __syncthreads();  // one wave/block: cheap; orders LDS write->read for the compiler
#pragma unroll
        for (int j = 0; j < ND; ++j) z[j] = zs[buf][j];  // conflict-free LDS broadcast
        zi = znew;
        buf ^= 1;
    }
}

extern "C" void kernel_launch(void* const* d_in, const int* in_sizes, int n_in,
                              void* d_out, int out_size, void* d_ws, size_t ws_size,
                              hipStream_t stream) {
    const float* z0 = (const float*)d_in[0];
    const float* sp = (const float*)d_in[1];
    const float* no = (const float*)d_in[2];
    const float* As = (const float*)d_in[3];
    const float* bs = (const float*)d_in[4];
    const float* Qc = (const float*)d_in[5];
    float* ys = (float*)d_out;

    slds_kernel<<<dim3(NBATCH), dim3(64), 0, stream>>>(z0, sp, no, As, bs, Qc, ys);
}

// Round 3
// 1477.439 us; speedup vs baseline: 1.2001x; 1.2001x over previous
//
#include <hip/hip_runtime.h>
#include <stdint.h>

#define NBATCH 512
#define NT     2048
#define NK     8
#define ND     32

// One wave (64 lanes) per batch element b. lane = (i = lane&31, kh = lane>>5).
// Each lane holds A[kh*4+kk][i][0..31] in 128 f32 VGPRs.
// z is broadcast via v_readlane into SGPRs each step: NO LDS, NO __syncthreads,
// so prefetched global loads are never drained by a barrier (the round-2 stall).
__global__ __launch_bounds__(64, 1) void slds_kernel(
    const float* __restrict__ z0,
    const float* __restrict__ s_probs,
    const float* __restrict__ noise,
    const float* __restrict__ A_s,
    const float* __restrict__ b_s,
    const float* __restrict__ Q_chol,
    float* __restrict__ ys)
{
    const int b    = blockIdx.x;
    const int lane = threadIdx.x;
    const int i    = lane & 31;
    const int kh   = lane >> 5;

    const float dt  = 0.05f;
    const float sdt = 0.22360679774997896f; // sqrt(0.05)

    // ---- A slice into registers (f32), 16B vector loads ----
    float a[4][ND];
#pragma unroll
    for (int kk = 0; kk < 4; ++kk) {
        const float4* ap = (const float4*)(A_s + (((size_t)(kh * 4 + kk) * ND + i) * ND));
#pragma unroll
        for (int q = 0; q < 8; ++q) {
            float4 v = ap[q];
            a[kk][q * 4 + 0] = v.x;
            a[kk][q * 4 + 1] = v.y;
            a[kk][q * 4 + 2] = v.z;
            a[kk][q * 4 + 3] = v.w;
        }
    }
    float breg[4], qreg[4];
#pragma unroll
    for (int kk = 0; kk < 4; ++kk) {
        breg[kk] = b_s[(kh * 4 + kk) * ND + i];
        qreg[kk] = Q_chol[(kh * 4 + kk) * ND + i];
    }

    // ---- z: own element + SGPR broadcast via readlane ----
    float zi = z0[b * ND + i];
    float z[ND];
#pragma unroll
    for (int j = 0; j < ND; ++j)
        z[j] = __int_as_float(__builtin_amdgcn_readlane(__float_as_int(zi), j));

    const float4* wbase = (const float4*)s_probs;  // [T][B][2] float4
    const float*  nbase = noise;

    // ---- 2-deep software pipeline for weights + noise (covers ~900cyc HBM miss) ----
    float4 wA[2], wB[2];
    float  nr[2];
#pragma unroll
    for (int u = 0; u < 2; ++u) {
        const size_t o = (size_t)u * NBATCH * 2 + (size_t)b * 2;
        wA[u] = wbase[o];
        wB[u] = wbase[o + 1];
        nr[u] = nbase[((size_t)u * NBATCH + b) * ND + i];
    }

    for (int t = 0; t < NT; t += 2) {
#pragma unroll
        for (int u = 0; u < 2; ++u) {
            const int tt = t + u;
            const float4 wa  = wA[u];
            const float4 wbv = wB[u];
            const float  nrc = nr[u];

            // prefetch step tt+2 into this slot (clamped; redundant tail load is harmless)
            int tp = tt + 2; if (tp > NT - 1) tp = NT - 1;
            const size_t op = (size_t)tp * NBATCH * 2 + (size_t)b * 2;
            wA[u] = wbase[op];
            wB[u] = wbase[op + 1];
            nr[u] = nbase[((size_t)tp * NBATCH + b) * ND + i];

            // 8 wave-uniform weights
            float w[8] = {wa.x, wa.y, wa.z, wa.w, wbv.x, wbv.y, wbv.z, wbv.w};
            float wsum = ((w[0] + w[1]) + (w[2] + w[3])) + ((w[4] + w[5]) + (w[6] + w[7]));
            float inv  = __builtin_amdgcn_rcpf(wsum);

            // y_k[i] = sum_j A[k][i][j] z[j]; w-weighted drift & diffusion
            float acc = 0.f, qacc = 0.f;
#pragma unroll
            for (int kk = 0; kk < 4; ++kk) {
                float y = 0.f;
#pragma unroll
                for (int j = 0; j < ND; ++j) y = fmaf(a[kk][j], z[j], y);
                float wk = (kh == 0) ? w[kk] : w[kk + 4];
                acc  = fmaf(wk, y + breg[kk], acc);
                qacc = fmaf(wk, qreg[kk], qacc);
            }

            // combine the two k-halves (single cross-lane op each)
            acc  += __shfl_xor(acc, 32);
            qacc += __shfl_xor(qacc, 32);

            float znew = zi + dt * (acc * inv) + (qacc * inv) * (sdt * nrc);

            const size_t oofs = ((size_t)tt * NBATCH + b) * ND + i;
            if (lane < 32) {
                __builtin_nontemporal_store(znew, &ys[oofs]);  // streamed, never re-read
            }

            // broadcast znew to all lanes' z[] via readlane (VALU only, no LDS/barrier)
#pragma unroll
            for (int j = 0; j < ND; ++j)
                z[j] = __int_as_float(__builtin_amdgcn_readlane(__float_as_int(znew), j));
            zi = znew;
        }
    }
}

extern "C" void kernel_launch(void* const* d_in, const int* in_sizes, int n_in,
                              void* d_out, int out_size, void* d_ws, size_t ws_size,
                              hipStream_t stream) {
    const float* z0 = (const float*)d_in[0];
    const float* sp = (const float*)d_in[1];
    const float* no = (const float*)d_in[2];
    const float* As = (const float*)d_in[3];
    const float* bs = (const float*)d_in[4];
    const float* Qc = (const float*)d_in[5];
    float* ys = (float*)d_out;

    slds_kernel<<<dim3(NBATCH), dim3(64), 0, stream>>>(z0, sp, no, As, bs, Qc, ys);
}